// Round 1
// baseline (951.185 us; speedup 1.0000x reference)
//
#include <hip/hip_runtime.h>
#include <hip/hip_bf16.h>
#include <math.h>

#define HH 240
#define WW 1216
#define BATCH 4
#define PROP 6
constexpr int HW = HH * WW;            // 291,840
constexpr int NPIX = BATCH * HW;       // 1,167,360
constexpr int NPART = 1024;

// ---------------------------------------------------------------------------
// Propagation: fused affinity (two 3x3 convs over 8 guidance ch) + mdconv
// (9-tap deformable bilinear gather over previous feat).
// One thread = one output pixel.
// ---------------------------------------------------------------------------
__global__ __launch_bounds__(256) void prop_kernel(
    const float* __restrict__ featPrev,   // [B][HW]
    const float* __restrict__ gbase,      // guidance + 8k*HW; batch stride 48*HW
    const float* __restrict__ aw,         // [9][8][3][3]
    const float* __restrict__ ab,         // [9]
    const float* __restrict__ ow,         // [16][8][3][3]
    const float* __restrict__ ob,         // [16]
    const float* __restrict__ w3,         // [9]
    const float* __restrict__ b3,         // [1]
    float* __restrict__ featNext)         // [B][HW]
{
    const int x = blockIdx.x * 256 + threadIdx.x;
    const int y = blockIdx.y;
    const int b = blockIdx.z;
    if (x >= WW) return;

    float acc[25];
#pragma unroll
    for (int o = 0; o < 9; ++o) acc[o] = ab[o];
#pragma unroll
    for (int o = 0; o < 16; ++o) acc[9 + o] = ob[o];

    const float* gb = gbase + (size_t)b * (48 * HW);

#pragma unroll 1
    for (int c = 0; c < 8; ++c) {
        const float* gc = gb + c * HW;
        float gv[9];
#pragma unroll
        for (int dy = -1; dy <= 1; ++dy) {
            const int yy = y + dy;
            const bool yok = ((unsigned)yy < (unsigned)HH);
            const int yc = min(max(yy, 0), HH - 1);
#pragma unroll
            for (int dx = -1; dx <= 1; ++dx) {
                const int xx = x + dx;
                const bool ok = yok && ((unsigned)xx < (unsigned)WW);
                const int xc = min(max(xx, 0), WW - 1);
                const float v = gc[yc * WW + xc];
                gv[(dy + 1) * 3 + (dx + 1)] = ok ? v : 0.0f;
            }
        }
#pragma unroll
        for (int t = 0; t < 9; ++t) {
            const float g = gv[t];
#pragma unroll
            for (int o = 0; o < 9; ++o)
                acc[o] = fmaf(g, aw[(o * 8 + c) * 9 + t], acc[o]);
#pragma unroll
            for (int o = 0; o < 16; ++o)
                acc[9 + o] = fmaf(g, ow[(o * 8 + c) * 9 + t], acc[9 + o]);
        }
    }

    // softmax-ish weight normalization: sigmoid then divide by (sum + 1e-8)
    float wg[9];
    float wsum = 1e-8f;
#pragma unroll
    for (int t = 0; t < 9; ++t) {
        const float s = 1.0f / (1.0f + __expf(-acc[t]));
        wg[t] = s;
        wsum += s;
    }
    const float winv = 1.0f / wsum;

    const float* fb = featPrev + (size_t)b * HW;
    float res = b3[0];
#pragma unroll
    for (int t = 0; t < 9; ++t) {
        float oy, ox;
        if (t < 4)       { oy = acc[9 + 2 * t];       ox = acc[10 + 2 * t]; }
        else if (t == 4) { oy = 0.0f;                 ox = 0.0f; }
        else             { oy = acc[9 + 2 * (t - 1)]; ox = acc[10 + 2 * (t - 1)]; }

        const float py = (float)(y - 1 + (t / 3)) + oy;
        const float px = (float)(x - 1 + (t % 3)) + ox;
        const float y0f = floorf(py), x0f = floorf(px);
        const float wy = py - y0f, wx = px - x0f;
        const int y0 = (int)y0f, x0i = (int)x0f;

        float s = 0.0f;
#pragma unroll
        for (int dy = 0; dy < 2; ++dy) {
            const int yy = y0 + dy;
            const bool yok = ((unsigned)yy < (unsigned)HH);
            const float wyf = dy ? wy : (1.0f - wy);
            const int yc = min(max(yy, 0), HH - 1);
#pragma unroll
            for (int dx = 0; dx < 2; ++dx) {
                const int xx = x0i + dx;
                const bool ok = yok && ((unsigned)xx < (unsigned)WW);
                const float wxf = dx ? wx : (1.0f - wx);
                const int xc = min(max(xx, 0), WW - 1);
                const float v = fb[yc * WW + xc];
                s = fmaf(wyf * wxf, ok ? v : 0.0f, s);
            }
        }
        res = fmaf(wg[t] * winv * w3[t], s, res);
    }
    featNext[(size_t)b * HW + y * WW + x] = res;
}

// ---------------------------------------------------------------------------
// Stage 1 of BN stats: per-block partial sums of y0,y1,y2 and their products.
// ---------------------------------------------------------------------------
__global__ __launch_bounds__(256) void stats_part(
    const float* __restrict__ y0s, const float* __restrict__ y1s,
    const float* __restrict__ y2s, float* __restrict__ part)
{
    float a[9] = {0, 0, 0, 0, 0, 0, 0, 0, 0};
    const int stride = gridDim.x * 256;
    for (int i = blockIdx.x * 256 + threadIdx.x; i < NPIX; i += stride) {
        const float v0 = y0s[i], v1 = y1s[i], v2 = y2s[i];
        a[0] += v0; a[1] += v1; a[2] += v2;
        a[3] = fmaf(v0, v0, a[3]); a[4] = fmaf(v0, v1, a[4]);
        a[5] = fmaf(v0, v2, a[5]); a[6] = fmaf(v1, v1, a[6]);
        a[7] = fmaf(v1, v2, a[7]); a[8] = fmaf(v2, v2, a[8]);
    }
    __shared__ float red[4][9];
    const int lane = threadIdx.x & 63, wv = threadIdx.x >> 6;
#pragma unroll
    for (int q = 0; q < 9; ++q) {
        float v = a[q];
        for (int o = 32; o; o >>= 1) v += __shfl_down(v, o, 64);
        if (lane == 0) red[wv][q] = v;
    }
    __syncthreads();
    if (threadIdx.x < 9) {
        const int q = threadIdx.x;
        part[blockIdx.x * 9 + q] = red[0][q] + red[1][q] + red[2][q] + red[3][q];
    }
}

// ---------------------------------------------------------------------------
// Stage 2: finalize per-channel BN scale/shift for sf = proj(y).
// mean/var of sf derived from first/second moments of y (1x1 conv identity).
// ---------------------------------------------------------------------------
__global__ __launch_bounds__(256) void stats_final(
    const float* __restrict__ part, const float* __restrict__ proj_w,
    const float* __restrict__ bn_g, const float* __restrict__ bn_b,
    float* __restrict__ stats)
{
    float a[9] = {0, 0, 0, 0, 0, 0, 0, 0, 0};
    for (int i = threadIdx.x; i < NPART; i += 256) {
#pragma unroll
        for (int q = 0; q < 9; ++q) a[q] += part[i * 9 + q];
    }
    __shared__ float red[4][9];
    const int lane = threadIdx.x & 63, wv = threadIdx.x >> 6;
#pragma unroll
    for (int q = 0; q < 9; ++q) {
        float v = a[q];
        for (int o = 32; o; o >>= 1) v += __shfl_down(v, o, 64);
        if (lane == 0) red[wv][q] = v;
    }
    __syncthreads();
    if (threadIdx.x == 0) {
        float s[9];
#pragma unroll
        for (int q = 0; q < 9; ++q) s[q] = red[0][q] + red[1][q] + red[2][q] + red[3][q];
        const float invN = 1.0f / (float)NPIX;
        const float m0 = s[0] * invN, m1 = s[1] * invN, m2 = s[2] * invN;
        const float E00 = s[3] * invN, E01 = s[4] * invN, E02 = s[5] * invN;
        const float E11 = s[6] * invN, E12 = s[7] * invN, E22 = s[8] * invN;
#pragma unroll
        for (int c = 0; c < 6; ++c) {
            const float p0 = proj_w[c * 3], p1 = proj_w[c * 3 + 1], p2 = proj_w[c * 3 + 2];
            const float mu = p0 * m0 + p1 * m1 + p2 * m2;
            const float e2 = p0 * p0 * E00 + p1 * p1 * E11 + p2 * p2 * E22 +
                             2.0f * (p0 * p1 * E01 + p0 * p2 * E02 + p1 * p2 * E12);
            const float var = e2 - mu * mu;
            const float sc = bn_g[c] / sqrtf(var + 1e-5f);
            stats[c] = sc;
            stats[6 + c] = bn_b[c] - mu * sc;
        }
    }
}

// ---------------------------------------------------------------------------
// Fused head: a1_pre(22ch) -> depthwise 3x3 + two 1x1 convs -> agg ->
// 3x3 sigmoid gate -> 1x1 -> sum(y*a).  Tile 32x8, halo 2.
// ---------------------------------------------------------------------------
__global__ __launch_bounds__(256) void head_kernel(
    const float* __restrict__ y0s, const float* __restrict__ y1s,
    const float* __restrict__ y2s, const float* __restrict__ attn,
    const float* __restrict__ stats,   // scale[6], shift[6]
    const float* __restrict__ proj_w,
    const float* __restrict__ c0_w, const float* __restrict__ c0_b,
    const float* __restrict__ cs_w, const float* __restrict__ cs_b,
    const float* __restrict__ c1_w, const float* __restrict__ c1_b,
    const float* __restrict__ c2_w, const float* __restrict__ c2_b,
    const float* __restrict__ csq_w, const float* __restrict__ csq_b,
    const float* __restrict__ cv_w, const float* __restrict__ cv_b,
    float* __restrict__ out)
{
    __shared__ float ap[22][432];    // a1_pre, ext tile 12x36 (halo 2)
    __shared__ float aggs[2][340];   // agg, tile+halo1 10x34
    __shared__ float a1s[11][256];   // a1 for center tile
    __shared__ float a2s[11][256];   // a2 for center tile

    const int tid = threadIdx.x;
    const int b = blockIdx.z;
    const int x0 = blockIdx.x * 32;
    const int y0t = blockIdx.y * 8;

    // ---- phase 1: a1_pre over ext tile (zero outside image = conv pad) ----
    for (int idx = tid; idx < 432; idx += 256) {
        const int eyl = idx / 36, exl = idx - eyl * 36;
        const int gy = y0t + eyl - 2, gx = x0 + exl - 2;
        float v[22];
        if (((unsigned)gy < (unsigned)HH) && ((unsigned)gx < (unsigned)WW)) {
            const size_t p = (size_t)gy * WW + gx;
            const float* abp = attn + (size_t)b * 16 * HW + p;
#pragma unroll
            for (int c = 0; c < 16; ++c)
                v[c] = fmaf(c0_w[c], abp[(size_t)c * HW], c0_b[c]);
            const float ym0 = y0s[(size_t)b * HW + p];
            const float ym1 = y1s[(size_t)b * HW + p];
            const float ym2 = y2s[(size_t)b * HW + p];
#pragma unroll
            for (int j = 0; j < 6; ++j) {
                const float sraw = proj_w[j * 3] * ym0 + proj_w[j * 3 + 1] * ym1 +
                                   proj_w[j * 3 + 2] * ym2;
                float sf = fmaf(stats[j], sraw, stats[6 + j]);
                sf = sf > 0.0f ? sf : 0.2f * sf;
                v[16 + j] = fmaf(c0_w[16 + j], sf, c0_b[16 + j]);
            }
        } else {
#pragma unroll
            for (int c = 0; c < 22; ++c) v[c] = 0.0f;
        }
#pragma unroll
        for (int c = 0; c < 22; ++c) ap[c][idx] = v[c];
    }
    __syncthreads();

    // ---- phase 2: dw3x3 + c1/c2 + agg over tile+halo1 ----
    for (int idx = tid; idx < 340; idx += 256) {
        const int ay = idx / 34, ax = idx - ay * 34;
        const int gy = y0t + ay - 1, gx = x0 + ax - 1;
        float m0 = 0.0f, m1 = 0.0f;
        const bool inimg = ((unsigned)gy < (unsigned)HH) && ((unsigned)gx < (unsigned)WW);
        if (inimg) {
            const int ey = ay + 1, ex = ax + 1;  // ext coords
            float a1[11], a2[11];
#pragma unroll
            for (int j = 0; j < 11; ++j) { a1[j] = c1_b[j]; a2[j] = c2_b[j]; }
#pragma unroll
            for (int c = 0; c < 22; ++c) {
                float dw = cs_b[c];
                float ctr = 0.0f;
#pragma unroll
                for (int t = 0; t < 9; ++t) {
                    const int dy = t / 3 - 1, dx = t % 3 - 1;
                    const float av = ap[c][(ey + dy) * 36 + (ex + dx)];
                    dw = fmaf(cs_w[c * 9 + t], av, dw);
                    if (t == 4) ctr = av;
                }
#pragma unroll
                for (int j = 0; j < 11; ++j) {
                    a1[j] = fmaf(c1_w[j * 22 + c], ctr, a1[j]);
                    a2[j] = fmaf(c2_w[j * 22 + c], dw, a2[j]);
                }
            }
            float sum = 0.0f, mx = -INFINITY;
#pragma unroll
            for (int j = 0; j < 11; ++j) {
                sum += a1[j] + a2[j];
                mx = fmaxf(mx, fmaxf(a1[j], a2[j]));
            }
            m0 = sum * (1.0f / 22.0f);
            m1 = mx;
            if (ay >= 1 && ay < 9 && ax >= 1 && ax < 33) {
                const int ci = (ay - 1) * 32 + (ax - 1);
#pragma unroll
                for (int j = 0; j < 11; ++j) { a1s[j][ci] = a1[j]; a2s[j][ci] = a2[j]; }
            }
        }
        aggs[0][idx] = m0;
        aggs[1][idx] = m1;
    }
    __syncthreads();

    // ---- phase 3: sigmoid gate + cv + final dot with y ----
    {
        const int ty = tid >> 5, tx = tid & 31;
        const int gy = y0t + ty, gx = x0 + tx;
        const int ay = ty + 1, ax = tx + 1;
        float z0 = csq_b[0], z1 = csq_b[1];
#pragma unroll
        for (int t = 0; t < 9; ++t) {
            const int dy = t / 3 - 1, dx = t % 3 - 1;
            const int ai = (ay + dy) * 34 + (ax + dx);
            const float g0 = aggs[0][ai], g1 = aggs[1][ai];
            z0 = fmaf(csq_w[t], g0, z0);
            z0 = fmaf(csq_w[9 + t], g1, z0);
            z1 = fmaf(csq_w[18 + t], g0, z1);
            z1 = fmaf(csq_w[27 + t], g1, z1);
        }
        const float s0 = 1.0f / (1.0f + __expf(-z0));
        const float s1 = 1.0f / (1.0f + __expf(-z1));
        const int ci = ty * 32 + tx;
        float av[11];
#pragma unroll
        for (int j = 0; j < 11; ++j) av[j] = a1s[j][ci] * s0 + a2s[j][ci] * s1;
        float v0 = cv_b[0], v1 = cv_b[1], v2 = cv_b[2];
#pragma unroll
        for (int j = 0; j < 11; ++j) {
            v0 = fmaf(cv_w[j], av[j], v0);
            v1 = fmaf(cv_w[11 + j], av[j], v1);
            v2 = fmaf(cv_w[22 + j], av[j], v2);
        }
        const size_t p = (size_t)b * HW + (size_t)gy * WW + gx;
        out[p] = y0s[p] * v0 + y1s[p] * v1 + y2s[p] * v2;
    }
}

// ---------------------------------------------------------------------------
extern "C" void kernel_launch(void* const* d_in, const int* in_sizes, int n_in,
                              void* d_out, int out_size, void* d_ws, size_t ws_size,
                              hipStream_t stream)
{
    (void)in_sizes; (void)n_in; (void)out_size; (void)ws_size;
    const float* feat_init = (const float*)d_in[0];
    const float* guidance  = (const float*)d_in[1];
    const float* attn      = (const float*)d_in[2];
    const float* aff_w_w   = (const float*)d_in[4];
    const float* aff_w_b   = (const float*)d_in[5];
    const float* aff_o_w   = (const float*)d_in[6];
    const float* aff_o_b   = (const float*)d_in[7];
    const float* w3        = (const float*)d_in[8];
    const float* b3        = (const float*)d_in[9];
    const float* proj_w    = (const float*)d_in[10];
    const float* bn_g      = (const float*)d_in[11];
    const float* bn_b      = (const float*)d_in[12];
    const float* c0_w      = (const float*)d_in[13];
    const float* c0_b      = (const float*)d_in[14];
    const float* cs_w      = (const float*)d_in[15];
    const float* cs_b      = (const float*)d_in[16];
    const float* c1_w      = (const float*)d_in[17];
    const float* c1_b      = (const float*)d_in[18];
    const float* c2_w      = (const float*)d_in[19];
    const float* c2_b      = (const float*)d_in[20];
    const float* csq_w     = (const float*)d_in[21];
    const float* csq_b     = (const float*)d_in[22];
    const float* cv_w      = (const float*)d_in[23];
    const float* cv_b      = (const float*)d_in[24];

    float* ws = (float*)d_ws;
    float* slot[5];
    for (int i = 0; i < 5; ++i) slot[i] = ws + (size_t)i * NPIX;
    float* part  = ws + (size_t)5 * NPIX;
    float* stats = part + (size_t)9 * NPART;

    const dim3 blk(256);
    const dim3 gp((WW + 255) / 256, HH, BATCH);

    // propagation chain; keep feats[3],[4],[5] in slots 2,3,4
    const int dst_ids[PROP] = {0, 1, 0, 2, 3, 4};
    const float* src = feat_init;
    for (int k = 0; k < PROP; ++k) {
        float* dst = slot[dst_ids[k]];
        prop_kernel<<<gp, blk, 0, stream>>>(
            src, guidance + (size_t)8 * k * HW,
            aff_w_w + (size_t)k * 648, aff_w_b + (size_t)k * 9,
            aff_o_w + (size_t)k * 1152, aff_o_b + (size_t)k * 16,
            w3, b3, dst);
        src = dst;
    }

    stats_part<<<dim3(NPART), blk, 0, stream>>>(slot[2], slot[3], slot[4], part);
    stats_final<<<dim3(1), blk, 0, stream>>>(part, proj_w, bn_g, bn_b, stats);

    head_kernel<<<dim3(WW / 32, HH / 8, BATCH), blk, 0, stream>>>(
        slot[2], slot[3], slot[4], attn, stats, proj_w,
        c0_w, c0_b, cs_w, cs_b, c1_w, c1_b, c2_w, c2_b,
        csq_w, csq_b, cv_w, cv_b, (float*)d_out);
}

// Round 2
// 932.216 us; speedup vs baseline: 1.0203x; 1.0203x over previous
//
#include <hip/hip_runtime.h>
#include <hip/hip_bf16.h>
#include <math.h>

#define HH 240
#define WW 1216
#define BATCH 4
#define PROP 6
constexpr int HW = HH * WW;            // 291,840
constexpr int NPIX = BATCH * HW;       // 1,167,360
constexpr int NPART = 1024;

// ---------------------------------------------------------------------------
// Propagation: fused affinity (two 3x3 convs over 8 guidance ch) + mdconv
// (9-tap deformable bilinear gather over previous feat).
// Tile 64x4, guidance staged in LDS with zero-pad so the conv inner loop is
// pure {ds_read imm-offset + fma}.
// ---------------------------------------------------------------------------
__global__ __launch_bounds__(256, 4) void prop_kernel(
    const float* __restrict__ featPrev,   // [B][HW]
    const float* __restrict__ gbase,      // guidance + 8k*HW; batch stride 48*HW
    const float* __restrict__ aw,         // [9][8][3][3]
    const float* __restrict__ ab,         // [9]
    const float* __restrict__ ow,         // [16][8][3][3]
    const float* __restrict__ ob,         // [16]
    const float* __restrict__ w3,         // [9]
    const float* __restrict__ b3,         // [1]
    float* __restrict__ featNext)         // [B][HW]
{
    __shared__ float gs[8 * 6 * 66];      // [ch][row 6][col 66], zero-padded

    const int tid = threadIdx.x;
    const int x0 = blockIdx.x * 64;
    const int y0t = blockIdx.y * 4;
    const int b = blockIdx.z;
    const float* gb = gbase + (size_t)b * (48 * HW);

    // ---- stage guidance ext tile (zero outside image = conv zero-pad) ----
    for (int idx = tid; idx < 8 * 6 * 66; idx += 256) {
        const int c = idx / 396;
        const int rem = idx - c * 396;
        const int r = rem / 66;
        const int col = rem - r * 66;
        const int gy = y0t + r - 1, gx = x0 + col - 1;
        float v = 0.0f;
        if (((unsigned)gy < (unsigned)HH) & ((unsigned)gx < (unsigned)WW))
            v = gb[c * HW + gy * WW + gx];
        gs[idx] = v;
    }
    __syncthreads();

    const int lx = tid & 63, ly = tid >> 6;
    const int x = x0 + lx, y = y0t + ly;

    float acc[25];
#pragma unroll
    for (int o = 0; o < 9; ++o) acc[o] = ab[o];
#pragma unroll
    for (int o = 0; o < 16; ++o) acc[9 + o] = ob[o];

    const float* gp0 = &gs[ly * 66 + lx];
#pragma unroll 1
    for (int c = 0; c < 8; ++c) {
        const float* gp = gp0 + c * 396;
        float gv[9];
#pragma unroll
        for (int dy = 0; dy < 3; ++dy)
#pragma unroll
            for (int dx = 0; dx < 3; ++dx)
                gv[dy * 3 + dx] = gp[dy * 66 + dx];   // ds_read, imm offsets
#pragma unroll
        for (int t = 0; t < 9; ++t) {
            const float g = gv[t];
#pragma unroll
            for (int o = 0; o < 9; ++o)
                acc[o] = fmaf(g, aw[(o * 8 + c) * 9 + t], acc[o]);
#pragma unroll
            for (int o = 0; o < 16; ++o)
                acc[9 + o] = fmaf(g, ow[(o * 8 + c) * 9 + t], acc[9 + o]);
        }
    }

    // sigmoid + normalize
    float wg[9];
    float wsum = 1e-8f;
#pragma unroll
    for (int t = 0; t < 9; ++t) {
        const float s = 1.0f / (1.0f + __expf(-acc[t]));
        wg[t] = s;
        wsum += s;
    }
    const float winv = 1.0f / wsum;

    // 9-tap deformable bilinear gather (32-bit offsets off SGPR base)
    const float* fb = featPrev + (size_t)b * HW;
    float sum = 0.0f;
#pragma unroll
    for (int t = 0; t < 9; ++t) {
        float oy, ox;
        if (t < 4)       { oy = acc[9 + 2 * t]; ox = acc[10 + 2 * t]; }
        else if (t == 4) { oy = 0.0f;           ox = 0.0f; }
        else             { oy = acc[7 + 2 * t]; ox = acc[8 + 2 * t]; }

        const float py = (float)(y - 1 + (t / 3)) + oy;
        const float px = (float)(x - 1 + (t % 3)) + ox;
        const float fy = floorf(py), fx = floorf(px);
        const float wy = py - fy, wx = px - fx;
        const int iy = (int)fy, ix = (int)fx;
        const int iy1 = iy + 1, ix1 = ix + 1;

        const int ry0 = min(max(iy, 0), HH - 1) * WW;
        const int ry1 = min(max(iy1, 0), HH - 1) * WW;
        const int cx0 = min(max(ix, 0), WW - 1);
        const int cx1 = min(max(ix1, 0), WW - 1);
        const float v00 = fb[ry0 + cx0], v01 = fb[ry0 + cx1];
        const float v10 = fb[ry1 + cx0], v11 = fb[ry1 + cx1];

        const bool vy0 = (unsigned)iy < (unsigned)HH;
        const bool vy1 = (unsigned)iy1 < (unsigned)HH;
        const bool vx0 = (unsigned)ix < (unsigned)WW;
        const bool vx1 = (unsigned)ix1 < (unsigned)WW;
        const float wy0 = 1.0f - wy, wx0 = 1.0f - wx;

        float s = 0.0f;
        s = fmaf((vy0 & vx0) ? wy0 * wx0 : 0.0f, v00, s);
        s = fmaf((vy0 & vx1) ? wy0 * wx  : 0.0f, v01, s);
        s = fmaf((vy1 & vx0) ? wy  * wx0 : 0.0f, v10, s);
        s = fmaf((vy1 & vx1) ? wy  * wx  : 0.0f, v11, s);

        sum = fmaf(wg[t] * w3[t], s, sum);
    }
    featNext[(size_t)b * HW + y * WW + x] = fmaf(winv, sum, b3[0]);
}

// ---------------------------------------------------------------------------
// Stage 1 of BN stats: per-block partial sums of y0,y1,y2 and their products.
// ---------------------------------------------------------------------------
__global__ __launch_bounds__(256) void stats_part(
    const float* __restrict__ y0s, const float* __restrict__ y1s,
    const float* __restrict__ y2s, float* __restrict__ part)
{
    float a[9] = {0, 0, 0, 0, 0, 0, 0, 0, 0};
    const int stride = gridDim.x * 256;
    for (int i = blockIdx.x * 256 + threadIdx.x; i < NPIX; i += stride) {
        const float v0 = y0s[i], v1 = y1s[i], v2 = y2s[i];
        a[0] += v0; a[1] += v1; a[2] += v2;
        a[3] = fmaf(v0, v0, a[3]); a[4] = fmaf(v0, v1, a[4]);
        a[5] = fmaf(v0, v2, a[5]); a[6] = fmaf(v1, v1, a[6]);
        a[7] = fmaf(v1, v2, a[7]); a[8] = fmaf(v2, v2, a[8]);
    }
    __shared__ float red[4][9];
    const int lane = threadIdx.x & 63, wv = threadIdx.x >> 6;
#pragma unroll
    for (int q = 0; q < 9; ++q) {
        float v = a[q];
        for (int o = 32; o; o >>= 1) v += __shfl_down(v, o, 64);
        if (lane == 0) red[wv][q] = v;
    }
    __syncthreads();
    if (threadIdx.x < 9) {
        const int q = threadIdx.x;
        part[blockIdx.x * 9 + q] = red[0][q] + red[1][q] + red[2][q] + red[3][q];
    }
}

// ---------------------------------------------------------------------------
// Stage 2: finalize per-channel BN scale/shift for sf = proj(y).
// ---------------------------------------------------------------------------
__global__ __launch_bounds__(256) void stats_final(
    const float* __restrict__ part, const float* __restrict__ proj_w,
    const float* __restrict__ bn_g, const float* __restrict__ bn_b,
    float* __restrict__ stats)
{
    float a[9] = {0, 0, 0, 0, 0, 0, 0, 0, 0};
    for (int i = threadIdx.x; i < NPART; i += 256) {
#pragma unroll
        for (int q = 0; q < 9; ++q) a[q] += part[i * 9 + q];
    }
    __shared__ float red[4][9];
    const int lane = threadIdx.x & 63, wv = threadIdx.x >> 6;
#pragma unroll
    for (int q = 0; q < 9; ++q) {
        float v = a[q];
        for (int o = 32; o; o >>= 1) v += __shfl_down(v, o, 64);
        if (lane == 0) red[wv][q] = v;
    }
    __syncthreads();
    if (threadIdx.x == 0) {
        float s[9];
#pragma unroll
        for (int q = 0; q < 9; ++q) s[q] = red[0][q] + red[1][q] + red[2][q] + red[3][q];
        const float invN = 1.0f / (float)NPIX;
        const float m0 = s[0] * invN, m1 = s[1] * invN, m2 = s[2] * invN;
        const float E00 = s[3] * invN, E01 = s[4] * invN, E02 = s[5] * invN;
        const float E11 = s[6] * invN, E12 = s[7] * invN, E22 = s[8] * invN;
#pragma unroll
        for (int c = 0; c < 6; ++c) {
            const float p0 = proj_w[c * 3], p1 = proj_w[c * 3 + 1], p2 = proj_w[c * 3 + 2];
            const float mu = p0 * m0 + p1 * m1 + p2 * m2;
            const float e2 = p0 * p0 * E00 + p1 * p1 * E11 + p2 * p2 * E22 +
                             2.0f * (p0 * p1 * E01 + p0 * p2 * E02 + p1 * p2 * E12);
            const float var = e2 - mu * mu;
            const float sc = bn_g[c] / sqrtf(var + 1e-5f);
            stats[c] = sc;
            stats[6 + c] = bn_b[c] - mu * sc;
        }
    }
}

// ---------------------------------------------------------------------------
// Fused head, tile 32x8. a1/a2 carried in registers (no LDS round-trip);
// 84 extra ring jobs fill the agg halo.
// ---------------------------------------------------------------------------
__global__ __launch_bounds__(256, 4) void head_kernel(
    const float* __restrict__ y0s, const float* __restrict__ y1s,
    const float* __restrict__ y2s, const float* __restrict__ attn,
    const float* __restrict__ stats,   // scale[6], shift[6]
    const float* __restrict__ proj_w,
    const float* __restrict__ c0_w, const float* __restrict__ c0_b,
    const float* __restrict__ cs_w, const float* __restrict__ cs_b,
    const float* __restrict__ c1_w, const float* __restrict__ c1_b,
    const float* __restrict__ c2_w, const float* __restrict__ c2_b,
    const float* __restrict__ csq_w, const float* __restrict__ csq_b,
    const float* __restrict__ cv_w, const float* __restrict__ cv_b,
    float* __restrict__ out)
{
    __shared__ float ap[22][432];    // a1_pre, ext tile 12x36 (halo 2)
    __shared__ float aggs[2][340];   // agg, tile+halo1 10x34

    const int tid = threadIdx.x;
    const int b = blockIdx.z;
    const int x0 = blockIdx.x * 32;
    const int y0t = blockIdx.y * 8;

    // ---- phase 1: a1_pre over ext tile (zero outside image = conv pad) ----
    for (int idx = tid; idx < 432; idx += 256) {
        const int eyl = idx / 36, exl = idx - eyl * 36;
        const int gy = y0t + eyl - 2, gx = x0 + exl - 2;
        float v[22];
        if (((unsigned)gy < (unsigned)HH) & ((unsigned)gx < (unsigned)WW)) {
            const size_t p = (size_t)gy * WW + gx;
            const float* abp = attn + (size_t)b * 16 * HW + p;
#pragma unroll
            for (int c = 0; c < 16; ++c)
                v[c] = fmaf(c0_w[c], abp[(size_t)c * HW], c0_b[c]);
            const float ym0 = y0s[(size_t)b * HW + p];
            const float ym1 = y1s[(size_t)b * HW + p];
            const float ym2 = y2s[(size_t)b * HW + p];
#pragma unroll
            for (int j = 0; j < 6; ++j) {
                const float sraw = proj_w[j * 3] * ym0 + proj_w[j * 3 + 1] * ym1 +
                                   proj_w[j * 3 + 2] * ym2;
                float sf = fmaf(stats[j], sraw, stats[6 + j]);
                sf = sf > 0.0f ? sf : 0.2f * sf;
                v[16 + j] = fmaf(c0_w[16 + j], sf, c0_b[16 + j]);
            }
        } else {
#pragma unroll
            for (int c = 0; c < 22; ++c) v[c] = 0.0f;
        }
#pragma unroll
        for (int c = 0; c < 22; ++c) ap[c][idx] = v[c];
    }
    __syncthreads();

    // computes a1[11], a2[11] at agg coords (ay,ax)
    auto compute_px = [&](int ay, int ax, float* a1, float* a2) {
        const int ey = ay + 1, ex = ax + 1;   // ext coords
#pragma unroll
        for (int j = 0; j < 11; ++j) { a1[j] = c1_b[j]; a2[j] = c2_b[j]; }
#pragma unroll
        for (int c = 0; c < 22; ++c) {
            float dw = cs_b[c];
            float ctr = 0.0f;
#pragma unroll
            for (int t = 0; t < 9; ++t) {
                const float av = ap[c][(ey + t / 3 - 1) * 36 + (ex + t % 3 - 1)];
                dw = fmaf(cs_w[c * 9 + t], av, dw);
                if (t == 4) ctr = av;
            }
#pragma unroll
            for (int j = 0; j < 11; ++j) {
                a1[j] = fmaf(c1_w[j * 22 + c], ctr, a1[j]);
                a2[j] = fmaf(c2_w[j * 22 + c], dw, a2[j]);
            }
        }
    };

    // ---- phase 2a: ring jobs (84 halo pixels of the 10x34 agg region) ----
    if (tid < 84) {
        int ay, ax;
        if (tid < 34)      { ay = 0; ax = tid; }
        else if (tid < 68) { ay = 9; ax = tid - 34; }
        else { const int s = tid - 68; ay = 1 + (s >> 1); ax = (s & 1) ? 33 : 0; }
        const int gy = y0t + ay - 1, gx = x0 + ax - 1;
        float m0 = 0.0f, m1 = 0.0f;
        if (((unsigned)gy < (unsigned)HH) & ((unsigned)gx < (unsigned)WW)) {
            float a1h[11], a2h[11];
            compute_px(ay, ax, a1h, a2h);
            float s = 0.0f, mx = -INFINITY;
#pragma unroll
            for (int j = 0; j < 11; ++j) {
                s += a1h[j] + a2h[j];
                mx = fmaxf(mx, fmaxf(a1h[j], a2h[j]));
            }
            m0 = s * (1.0f / 22.0f);
            m1 = mx;
        }
        aggs[0][ay * 34 + ax] = m0;
        aggs[1][ay * 34 + ax] = m1;
    }

    // ---- phase 2b: center pixel, keep a1/a2 in registers ----
    const int ty = tid >> 5, tx = tid & 31;
    const int ay = ty + 1, ax = tx + 1;
    float a1[11], a2[11];
    compute_px(ay, ax, a1, a2);
    {
        float s = 0.0f, mx = -INFINITY;
#pragma unroll
        for (int j = 0; j < 11; ++j) {
            s += a1[j] + a2[j];
            mx = fmaxf(mx, fmaxf(a1[j], a2[j]));
        }
        aggs[0][ay * 34 + ax] = s * (1.0f / 22.0f);
        aggs[1][ay * 34 + ax] = mx;
    }
    __syncthreads();

    // ---- phase 3: sigmoid gate + cv + final dot with y ----
    float z0 = csq_b[0], z1 = csq_b[1];
#pragma unroll
    for (int t = 0; t < 9; ++t) {
        const int ai = (ay + t / 3 - 1) * 34 + (ax + t % 3 - 1);
        const float g0 = aggs[0][ai], g1 = aggs[1][ai];
        z0 = fmaf(csq_w[t], g0, fmaf(csq_w[9 + t], g1, z0));
        z1 = fmaf(csq_w[18 + t], g0, fmaf(csq_w[27 + t], g1, z1));
    }
    const float s0 = 1.0f / (1.0f + __expf(-z0));
    const float s1 = 1.0f / (1.0f + __expf(-z1));
    float v0 = cv_b[0], v1 = cv_b[1], v2 = cv_b[2];
#pragma unroll
    for (int j = 0; j < 11; ++j) {
        const float av = a1[j] * s0 + a2[j] * s1;
        v0 = fmaf(cv_w[j], av, v0);
        v1 = fmaf(cv_w[11 + j], av, v1);
        v2 = fmaf(cv_w[22 + j], av, v2);
    }
    const size_t p = (size_t)b * HW + (size_t)(y0t + ty) * WW + (x0 + tx);
    out[p] = y0s[p] * v0 + y1s[p] * v1 + y2s[p] * v2;
}

// ---------------------------------------------------------------------------
extern "C" void kernel_launch(void* const* d_in, const int* in_sizes, int n_in,
                              void* d_out, int out_size, void* d_ws, size_t ws_size,
                              hipStream_t stream)
{
    (void)in_sizes; (void)n_in; (void)out_size; (void)ws_size;
    const float* feat_init = (const float*)d_in[0];
    const float* guidance  = (const float*)d_in[1];
    const float* attn      = (const float*)d_in[2];
    const float* aff_w_w   = (const float*)d_in[4];
    const float* aff_w_b   = (const float*)d_in[5];
    const float* aff_o_w   = (const float*)d_in[6];
    const float* aff_o_b   = (const float*)d_in[7];
    const float* w3        = (const float*)d_in[8];
    const float* b3        = (const float*)d_in[9];
    const float* proj_w    = (const float*)d_in[10];
    const float* bn_g      = (const float*)d_in[11];
    const float* bn_b      = (const float*)d_in[12];
    const float* c0_w      = (const float*)d_in[13];
    const float* c0_b      = (const float*)d_in[14];
    const float* cs_w      = (const float*)d_in[15];
    const float* cs_b      = (const float*)d_in[16];
    const float* c1_w      = (const float*)d_in[17];
    const float* c1_b      = (const float*)d_in[18];
    const float* c2_w      = (const float*)d_in[19];
    const float* c2_b      = (const float*)d_in[20];
    const float* csq_w     = (const float*)d_in[21];
    const float* csq_b     = (const float*)d_in[22];
    const float* cv_w      = (const float*)d_in[23];
    const float* cv_b      = (const float*)d_in[24];

    float* ws = (float*)d_ws;
    float* slot[5];
    for (int i = 0; i < 5; ++i) slot[i] = ws + (size_t)i * NPIX;
    float* part  = ws + (size_t)5 * NPIX;
    float* stats = part + (size_t)9 * NPART;

    const dim3 blk(256);
    const dim3 gp(WW / 64, HH / 4, BATCH);

    // propagation chain; keep feats[3],[4],[5] in slots 2,3,4
    const int dst_ids[PROP] = {0, 1, 0, 2, 3, 4};
    const float* src = feat_init;
    for (int k = 0; k < PROP; ++k) {
        float* dst = slot[dst_ids[k]];
        prop_kernel<<<gp, blk, 0, stream>>>(
            src, guidance + (size_t)8 * k * HW,
            aff_w_w + (size_t)k * 648, aff_w_b + (size_t)k * 9,
            aff_o_w + (size_t)k * 1152, aff_o_b + (size_t)k * 16,
            w3, b3, dst);
        src = dst;
    }

    stats_part<<<dim3(NPART), blk, 0, stream>>>(slot[2], slot[3], slot[4], part);
    stats_final<<<dim3(1), blk, 0, stream>>>(part, proj_w, bn_g, bn_b, stats);

    head_kernel<<<dim3(WW / 32, HH / 8, BATCH), blk, 0, stream>>>(
        slot[2], slot[3], slot[4], attn, stats, proj_w,
        c0_w, c0_b, cs_w, cs_b, c1_w, c1_b, c2_w, c2_b,
        csq_w, csq_b, cv_w, cv_b, (float*)d_out);
}